// Round 22
// baseline (276.339 us; speedup 1.0000x reference)
//
#include <hip/hip_runtime.h>
#include <hip/hip_fp16.h>
#include <math.h>

#define NN 50000
#define DD 128
#define NCLS 40
#define EPSV 1e-8f
#define ELLCAP 64

typedef unsigned int uint4n __attribute__((ext_vector_type(4)));

__device__ __forceinline__ float waveReduceSum(float v) {
    for (int off = 32; off > 0; off >>= 1) v += __shfl_xor(v, off, 64);
    return v;
}

__device__ __forceinline__ float bcastlane0(float v) {
    return __int_as_float(__builtin_amdgcn_readfirstlane(__float_as_int(v)));
}

__device__ __forceinline__ float h_lo(unsigned int w) {
    return __half2float(__ushort_as_half((unsigned short)(w & 0xffffu)));
}
__device__ __forceinline__ float h_hi(unsigned int w) {
    return __half2float(__ushort_as_half((unsigned short)(w >> 16)));
}
__device__ __forceinline__ unsigned int h_pack(float a, float b) {
    return (unsigned int)__half_as_ushort(__float2half(a)) |
           ((unsigned int)__half_as_ushort(__float2half(b)) << 16);
}
__device__ __forceinline__ float fexp(float x) {
    return __builtin_amdgcn_exp2f(x * 1.44269504089f);
}
__device__ __forceinline__ float frcp(float x) { return __builtin_amdgcn_rcpf(x); }
__device__ __forceinline__ float frsq(float x) { return __builtin_amdgcn_rsqf(x); }

// ---------------- ELL build ----------------

__global__ void fill_ell_kernel(const int* __restrict__ erow, const int* __restrict__ ecol,
                                const float* __restrict__ ew, int* __restrict__ cnt,
                                unsigned int* __restrict__ ell, int E) {
    for (int e = blockIdx.x * blockDim.x + threadIdx.x; e < E; e += gridDim.x * blockDim.x) {
        int r = erow[e];
        int p = atomicAdd(&cnt[r], 1);
        if (p < ELLCAP) {
            unsigned int packed = (unsigned int)ecol[e] |
                ((unsigned int)__half_as_ushort(__float2half(ew[e])) << 16);
            ell[(long)r * ELLCAP + p] = packed;
        }
    }
}

__global__ void packwt_kernel(const float* __restrict__ W1, unsigned int* __restrict__ p1,
                              const float* __restrict__ W2, unsigned int* __restrict__ p2) {
    int b = blockIdx.x;
    const float* W = (b < 32) ? W1 : W2;
    unsigned int* P = (b < 32) ? p1 : p2;
    int a = (b & 31) * 256 + threadIdx.x;
    int pr = a >> 7;
    int rem = a & 127;
    int l = rem >> 1, kl = rem & 1;
    int k = 2 * pr + kl;
    P[a] = h_pack(W[(2 * l) * 128 + k], W[(2 * l + 1) * 128 + k]);
}

// ---------------- linear1: expmap + GEMM(fp16 W in LDS) + lorentz, fp16 out ----------------
#define RPW 8
__global__ __launch_bounds__(256, 4) void linear1_kernel(
    const float* __restrict__ X, const unsigned int* __restrict__ Wp,
    const float* __restrict__ bias, const float* __restrict__ logs,
    unsigned int* __restrict__ outh, int n)
{
    __shared__ unsigned int wS[8192];
    __shared__ float xrow[4][RPW * 128];
    int tid = threadIdx.x;
    int wid = tid >> 6, lane = tid & 63;
    #pragma unroll
    for (int i = 0; i < 8; ++i) {
        int idx = tid * 4 + i * 1024;
        *(uint4n*)(wS + idx) = *(const uint4n*)(Wp + idx);
    }
    __syncthreads();
    float2 bv = *(const float2*)(bias + 2 * lane);
    float sval = fminf(fexp(logs[0]), 10.f);
    float* xbase = xrow[wid];
    int nslabs = n / RPW;
    for (int slab = blockIdx.x * 4 + wid; slab < nslabs; slab += gridDim.x * 4) {
        int row0 = slab * RPW;
        #pragma unroll
        for (int r = 0; r < RPW; ++r) {
            int row = row0 + r;
            const float* src = X + (long)row * 127;
            float u0 = src[2 * lane];
            float u1 = (2 * lane + 1 < 127) ? src[2 * lane + 1] : 0.f;
            float ss = waveReduceSum(u0 * u0 + u1 * u1);
            float nrm = fmaxf(sqrtf(ss), EPSV);
            float ex = fexp(nrm), exn = fexp(-nrm);
            float ch = 0.5f * (ex + exn);
            float coef = 0.5f * (ex - exn) * frcp(nrm);
            if (lane == 0) xbase[r * 128] = ch;
            xbase[r * 128 + 1 + 2 * lane] = coef * u0;
            if (2 * lane + 1 < 127) xbase[r * 128 + 2 + 2 * lane] = coef * u1;
        }
        float2 acc[RPW];
        #pragma unroll
        for (int r = 0; r < RPW; ++r) acc[r] = make_float2(0.f, 0.f);
        #pragma unroll 4
        for (int k0 = 0; k0 < 128; k0 += 4) {
            uint2 wa = *(const uint2*)(wS + (k0 >> 1) * 128 + 2 * lane);
            uint2 wb = *(const uint2*)(wS + (k0 >> 1) * 128 + 128 + 2 * lane);
            float2 w0 = make_float2(h_lo(wa.x), h_hi(wa.x));
            float2 w1 = make_float2(h_lo(wa.y), h_hi(wa.y));
            float2 w2 = make_float2(h_lo(wb.x), h_hi(wb.x));
            float2 w3 = make_float2(h_lo(wb.y), h_hi(wb.y));
            #pragma unroll
            for (int r = 0; r < RPW; ++r) {
                float4 xq = *(const float4*)(xbase + r * 128 + k0);
                acc[r].x = fmaf(xq.x, w0.x, acc[r].x);
                acc[r].y = fmaf(xq.x, w0.y, acc[r].y);
                acc[r].x = fmaf(xq.y, w1.x, acc[r].x);
                acc[r].y = fmaf(xq.y, w1.y, acc[r].y);
                acc[r].x = fmaf(xq.z, w2.x, acc[r].x);
                acc[r].y = fmaf(xq.z, w2.y, acc[r].y);
                acc[r].x = fmaf(xq.w, w3.x, acc[r].x);
                acc[r].y = fmaf(xq.w, w3.y, acc[r].y);
            }
        }
        #pragma unroll
        for (int r = 0; r < RPW; ++r) {
            float ax = acc[r].x + bv.x;
            float ay = acc[r].y + bv.y;
            float t0 = __shfl(ax, 0, 64);
            float ssq = waveReduceSum(ax * ax + ay * ay);
            float timev = sval * frcp(1.f + fexp(-t0)) + 1.5f;
            float sq = fmaxf(ssq - t0 * t0, EPSV);
            float fac = sqrtf(fmaxf((timev * timev - 1.f) * frcp(sq), EPSV));
            float o0 = (lane == 0) ? timev : ax * fac;
            __builtin_nontemporal_store(h_pack(o0, ay * fac),
                                        &outh[(long)(row0 + r) * 64 + lane]);
        }
    }
}

// ---------------- linear2 ----------------
__global__ __launch_bounds__(256, 4) void linear2_kernel(
    const unsigned int* __restrict__ Xh, const unsigned int* __restrict__ Wp,
    const float* __restrict__ bias, const float* __restrict__ logs,
    unsigned int* __restrict__ outh, int n)
{
    __shared__ unsigned int wS[8192];
    __shared__ float xrow[4][RPW * 128];
    int tid = threadIdx.x;
    int wid = tid >> 6, lane = tid & 63;
    #pragma unroll
    for (int i = 0; i < 8; ++i) {
        int idx = tid * 4 + i * 1024;
        *(uint4n*)(wS + idx) = *(const uint4n*)(Wp + idx);
    }
    __syncthreads();
    float2 bv = *(const float2*)(bias + 2 * lane);
    float sval = fminf(fexp(logs[0]), 10.f);
    float* xbase = xrow[wid];
    int nslabs = n / RPW;
    for (int slab = blockIdx.x * 4 + wid; slab < nslabs; slab += gridDim.x * 4) {
        int row0 = slab * RPW;
        #pragma unroll
        for (int r = 0; r < RPW; ++r) {
            unsigned int u = __builtin_nontemporal_load(&Xh[(long)(row0 + r) * 64 + lane]);
            *(float2*)(xbase + r * 128 + 2 * lane) = make_float2(h_lo(u), h_hi(u));
        }
        float2 acc[RPW];
        #pragma unroll
        for (int r = 0; r < RPW; ++r) acc[r] = make_float2(0.f, 0.f);
        #pragma unroll 4
        for (int k0 = 0; k0 < 128; k0 += 4) {
            uint2 wa = *(const uint2*)(wS + (k0 >> 1) * 128 + 2 * lane);
            uint2 wb = *(const uint2*)(wS + (k0 >> 1) * 128 + 128 + 2 * lane);
            float2 w0 = make_float2(h_lo(wa.x), h_hi(wa.x));
            float2 w1 = make_float2(h_lo(wa.y), h_hi(wa.y));
            float2 w2 = make_float2(h_lo(wb.x), h_hi(wb.x));
            float2 w3 = make_float2(h_lo(wb.y), h_hi(wb.y));
            #pragma unroll
            for (int r = 0; r < RPW; ++r) {
                float4 xq = *(const float4*)(xbase + r * 128 + k0);
                acc[r].x = fmaf(xq.x, w0.x, acc[r].x);
                acc[r].y = fmaf(xq.x, w0.y, acc[r].y);
                acc[r].x = fmaf(xq.y, w1.x, acc[r].x);
                acc[r].y = fmaf(xq.y, w1.y, acc[r].y);
                acc[r].x = fmaf(xq.z, w2.x, acc[r].x);
                acc[r].y = fmaf(xq.z, w2.y, acc[r].y);
                acc[r].x = fmaf(xq.w, w3.x, acc[r].x);
                acc[r].y = fmaf(xq.w, w3.y, acc[r].y);
            }
        }
        #pragma unroll
        for (int r = 0; r < RPW; ++r) {
            float ax = acc[r].x + bv.x;
            float ay = acc[r].y + bv.y;
            float t0 = __shfl(ax, 0, 64);
            float ssq = waveReduceSum(ax * ax + ay * ay);
            float timev = sval * frcp(1.f + fexp(-t0)) + 1.5f;
            float sq = fmaxf(ssq - t0 * t0, EPSV);
            float fac = sqrtf(fmaxf((timev * timev - 1.f) * frcp(sq), EPSV));
            float o0 = (lane == 0) ? timev : ax * fac;
            __builtin_nontemporal_store(h_pack(o0, ay * fac),
                                        &outh[(long)(row0 + r) * 64 + lane]);
        }
    }
}

// ---------------- gather: 2 rows/wave, 4-edge batched loads (8 X-loads in flight) ----
// edge = packed uint: col (low 16) | fp16 weight (high 16). packed 0 => col 0, w=+0.

#define GBATCH(accs, eptr, ia, cc)                                         \
    {                                                                      \
        unsigned int cw0 = eptr[ia];                                       \
        unsigned int cw1 = (ia + 4  < cc) ? eptr[ia + 4]  : 0u;            \
        unsigned int cw2 = (ia + 8  < cc) ? eptr[ia + 8]  : 0u;            \
        unsigned int cw3 = (ia + 12 < cc) ? eptr[ia + 12] : 0u;            \
        uint4 x0 = *(const uint4*)(Xh + (long)(cw0 & 0xffffu) * 64 + l16 * 4); \
        uint4 x1 = *(const uint4*)(Xh + (long)(cw1 & 0xffffu) * 64 + l16 * 4); \
        uint4 x2 = *(const uint4*)(Xh + (long)(cw2 & 0xffffu) * 64 + l16 * 4); \
        uint4 x3 = *(const uint4*)(Xh + (long)(cw3 & 0xffffu) * 64 + l16 * 4); \
        float w0 = h_hi(cw0), w1 = h_hi(cw1), w2 = h_hi(cw2), w3 = h_hi(cw3); \
        accs[0] = fmaf(w0, h_lo(x0.x), accs[0]); accs[1] = fmaf(w0, h_hi(x0.x), accs[1]); \
        accs[2] = fmaf(w0, h_lo(x0.y), accs[2]); accs[3] = fmaf(w0, h_hi(x0.y), accs[3]); \
        accs[4] = fmaf(w0, h_lo(x0.z), accs[4]); accs[5] = fmaf(w0, h_hi(x0.z), accs[5]); \
        accs[6] = fmaf(w0, h_lo(x0.w), accs[6]); accs[7] = fmaf(w0, h_hi(x0.w), accs[7]); \
        accs[0] = fmaf(w1, h_lo(x1.x), accs[0]); accs[1] = fmaf(w1, h_hi(x1.x), accs[1]); \
        accs[2] = fmaf(w1, h_lo(x1.y), accs[2]); accs[3] = fmaf(w1, h_hi(x1.y), accs[3]); \
        accs[4] = fmaf(w1, h_lo(x1.z), accs[4]); accs[5] = fmaf(w1, h_hi(x1.z), accs[5]); \
        accs[6] = fmaf(w1, h_lo(x1.w), accs[6]); accs[7] = fmaf(w1, h_hi(x1.w), accs[7]); \
        accs[0] = fmaf(w2, h_lo(x2.x), accs[0]); accs[1] = fmaf(w2, h_hi(x2.x), accs[1]); \
        accs[2] = fmaf(w2, h_lo(x2.y), accs[2]); accs[3] = fmaf(w2, h_hi(x2.y), accs[3]); \
        accs[4] = fmaf(w2, h_lo(x2.z), accs[4]); accs[5] = fmaf(w2, h_hi(x2.z), accs[5]); \
        accs[6] = fmaf(w2, h_lo(x2.w), accs[6]); accs[7] = fmaf(w2, h_hi(x2.w), accs[7]); \
        accs[0] = fmaf(w3, h_lo(x3.x), accs[0]); accs[1] = fmaf(w3, h_hi(x3.x), accs[1]); \
        accs[2] = fmaf(w3, h_lo(x3.y), accs[2]); accs[3] = fmaf(w3, h_hi(x3.y), accs[3]); \
        accs[4] = fmaf(w3, h_lo(x3.z), accs[4]); accs[5] = fmaf(w3, h_hi(x3.z), accs[5]); \
        accs[6] = fmaf(w3, h_lo(x3.w), accs[6]); accs[7] = fmaf(w3, h_hi(x3.w), accs[7]); \
    }

#define REDUCE8(accs)                                                      \
    _Pragma("unroll")                                                      \
    for (int q = 0; q < 8; ++q) {                                          \
        accs[q] += __shfl_xor(accs[q], 16, 64);                            \
        accs[q] += __shfl_xor(accs[q], 32, 64);                            \
    }

#define GATHER_PAIR()                                                      \
    int rowA = 2 * pair, rowB = rowA + 1;                                  \
    int cA = min(cnt[rowA], ELLCAP), cB = min(cnt[rowB], ELLCAP);          \
    const unsigned int* eA = ell + (long)rowA * ELLCAP;                    \
    const unsigned int* eB = ell + (long)rowB * ELLCAP;                    \
    float aA[8] = {0,0,0,0,0,0,0,0};                                       \
    float aB[8] = {0,0,0,0,0,0,0,0};                                       \
    {                                                                      \
        int ia = g, ib = g;                                                \
        while (ia < cA && ib < cB) {                                       \
            GBATCH(aA, eA, ia, cA)                                         \
            GBATCH(aB, eB, ib, cB)                                         \
            ia += 16; ib += 16;                                            \
        }                                                                  \
        while (ia < cA) { GBATCH(aA, eA, ia, cA) ia += 16; }               \
        while (ib < cB) { GBATCH(aB, eB, ib, cB) ib += 16; }               \
    }                                                                      \
    REDUCE8(aA)                                                            \
    REDUCE8(aB)

#define SS16(ss)                                                           \
    ss += __shfl_xor(ss, 1, 64); ss += __shfl_xor(ss, 2, 64);              \
    ss += __shfl_xor(ss, 4, 64); ss += __shfl_xor(ss, 8, 64);

// ---------------- agg1 + lorentz-normalize + relu -> fp16 ----------------
__global__ __launch_bounds__(256, 8) void gather_norm_kernel(
    const unsigned int* __restrict__ Xh, const int* __restrict__ cnt,
    const unsigned int* __restrict__ ell, unsigned int* __restrict__ outh, int n)
{
    int wid = threadIdx.x >> 6, lane = threadIdx.x & 63;
    int g = lane >> 4, l16 = lane & 15;
    int npairs = n >> 1;
    for (int pair = blockIdx.x * 4 + wid; pair < npairs; pair += gridDim.x * 4) {
        GATHER_PAIR()
        float ssA = aA[0]*aA[0]+aA[1]*aA[1]+aA[2]*aA[2]+aA[3]*aA[3]
                  + aA[4]*aA[4]+aA[5]*aA[5]+aA[6]*aA[6]+aA[7]*aA[7];
        float ssB = aB[0]*aB[0]+aB[1]*aB[1]+aB[2]*aB[2]+aB[3]*aB[3]
                  + aB[4]*aB[4]+aB[5]*aB[5]+aB[6]*aB[6]+aB[7]*aB[7];
        SS16(ssA)
        SS16(ssB)
        float t0A = bcastlane0(aA[0]);
        float t0B = bcastlane0(aB[0]);
        float invA = frsq(fmaxf(fabsf(2.f * t0A * t0A - ssA), EPSV));
        float invB = frsq(fmaxf(fabsf(2.f * t0B * t0B - ssB), EPSV));
        if (g == 0) {
            uint4n o;
            o.x = h_pack(fmaxf(aA[0]*invA,0.f), fmaxf(aA[1]*invA,0.f));
            o.y = h_pack(fmaxf(aA[2]*invA,0.f), fmaxf(aA[3]*invA,0.f));
            o.z = h_pack(fmaxf(aA[4]*invA,0.f), fmaxf(aA[5]*invA,0.f));
            o.w = h_pack(fmaxf(aA[6]*invA,0.f), fmaxf(aA[7]*invA,0.f));
            __builtin_nontemporal_store(o, (uint4n*)(outh + (long)rowA * 64 + l16 * 4));
        } else if (g == 1) {
            uint4n o;
            o.x = h_pack(fmaxf(aB[0]*invB,0.f), fmaxf(aB[1]*invB,0.f));
            o.y = h_pack(fmaxf(aB[2]*invB,0.f), fmaxf(aB[3]*invB,0.f));
            o.z = h_pack(fmaxf(aB[4]*invB,0.f), fmaxf(aB[5]*invB,0.f));
            o.w = h_pack(fmaxf(aB[6]*invB,0.f), fmaxf(aB[7]*invB,0.f));
            __builtin_nontemporal_store(o, (uint4n*)(outh + (long)rowB * 64 + l16 * 4));
        }
    }
}

// ---------------- agg2 + lorentz-normalize + sign-flip + logits ----------------
__global__ __launch_bounds__(256, 8) void gather_logits_kernel(
    const unsigned int* __restrict__ Xh, const int* __restrict__ cnt,
    const unsigned int* __restrict__ ell,
    const float* __restrict__ cls, const float* __restrict__ cbias,
    float* __restrict__ outp, int n)
{
    __shared__ unsigned int clsP[NCLS * 66];
    __shared__ float cbS[NCLS];
    __shared__ float xsrow[4][2][128];
    int tid = threadIdx.x;
    for (int idx = tid; idx < NCLS * 64; idx += 256) {
        int c = idx >> 6, kk = idx & 63;
        clsP[c * 66 + kk] = h_pack(cls[c * 128 + 2 * kk], cls[c * 128 + 2 * kk + 1]);
    }
    if (tid < NCLS) cbS[tid] = cbias[tid];
    __syncthreads();
    int wid = tid >> 6, lane = tid & 63;
    int g = lane >> 4, l16 = lane & 15;
    float* xsA = xsrow[wid][0];
    float* xsB = xsrow[wid][1];
    int npairs = n >> 1;
    for (int pair = blockIdx.x * 4 + wid; pair < npairs; pair += gridDim.x * 4) {
        GATHER_PAIR()
        float ssA = aA[0]*aA[0]+aA[1]*aA[1]+aA[2]*aA[2]+aA[3]*aA[3]
                  + aA[4]*aA[4]+aA[5]*aA[5]+aA[6]*aA[6]+aA[7]*aA[7];
        float ssB = aB[0]*aB[0]+aB[1]*aB[1]+aB[2]*aB[2]+aB[3]*aB[3]
                  + aB[4]*aB[4]+aB[5]*aB[5]+aB[6]*aB[6]+aB[7]*aB[7];
        SS16(ssA)
        SS16(ssB)
        float t0A = bcastlane0(aA[0]);
        float t0B = bcastlane0(aB[0]);
        float invA = frsq(fmaxf(fabsf(2.f * t0A * t0A - ssA), EPSV));
        float invB = frsq(fmaxf(fabsf(2.f * t0B * t0B - ssB), EPSV));
        if (g == 0) {
            float v0 = aA[0] * invA;
            if (l16 == 0) v0 = -v0;
            float* xp = xsA + l16 * 8;
            *(float4*)xp       = make_float4(v0, aA[1]*invA, aA[2]*invA, aA[3]*invA);
            *(float4*)(xp + 4) = make_float4(aA[4]*invA, aA[5]*invA, aA[6]*invA, aA[7]*invA);
        } else if (g == 1) {
            float v0 = aB[0] * invB;
            if (l16 == 0) v0 = -v0;
            float* xp = xsB + l16 * 8;
            *(float4*)xp       = make_float4(v0, aB[1]*invB, aB[2]*invB, aB[3]*invB);
            *(float4*)(xp + 4) = make_float4(aB[4]*invB, aB[5]*invB, aB[6]*invB, aB[7]*invB);
        }
        if (lane < NCLS) {
            float dA = 0.f, dB = 0.f;
            const unsigned int* cp = clsP + lane * 66;
            #pragma unroll 8
            for (int kk = 0; kk < 64; ++kk) {
                unsigned int u = cp[kk];
                float c0 = h_lo(u), c1 = h_hi(u);
                float2 xa = *(const float2*)(xsA + 2 * kk);
                float2 xb = *(const float2*)(xsB + 2 * kk);
                dA = fmaf(c0, xa.x, dA); dA = fmaf(c1, xa.y, dA);
                dB = fmaf(c0, xb.x, dB); dB = fmaf(c1, xb.y, dB);
            }
            outp[(long)rowA * NCLS + lane] = 2.f + 2.f * dA + cbS[lane];
            outp[(long)rowB * NCLS + lane] = 2.f + 2.f * dB + cbS[lane];
        }
    }
}

// ---------------- launch ----------------

extern "C" void kernel_launch(void* const* d_in, const int* in_sizes, int n_in,
                              void* d_out, int out_size, void* d_ws, size_t ws_size,
                              hipStream_t stream) {
    const float* node_feat = (const float*)d_in[0];
    const float* W1   = (const float*)d_in[1];
    const float* b1   = (const float*)d_in[2];
    const float* s1   = (const float*)d_in[3];
    const float* W2   = (const float*)d_in[4];
    const float* b2   = (const float*)d_in[5];
    const float* s2   = (const float*)d_in[6];
    const float* cls  = (const float*)d_in[7];
    const float* cb   = (const float*)d_in[8];
    const float* ew   = (const float*)d_in[9];
    const int*   erow = (const int*)d_in[10];
    const int*   ecol = (const int*)d_in[11];
    float* outp = (float*)d_out;

    const int n = NN;
    const int E = in_sizes[9];

    unsigned int* bufH1 = (unsigned int*)d_ws;
    unsigned int* bufH2 = bufH1 + (size_t)NN * 64;
    int*   cnt    = (int*)(bufH2 + (size_t)NN * 64);
    unsigned int* ell = (unsigned int*)(cnt + NN);
    unsigned int* wp1 = ell + (size_t)NN * ELLCAP;
    unsigned int* wp2 = wp1 + 128 * 64;

    (void)hipMemsetAsync(cnt, 0, (size_t)NN * sizeof(int), stream);
    packwt_kernel<<<64, 256, 0, stream>>>(W1, wp1, W2, wp2);
    fill_ell_kernel<<<2048, 256, 0, stream>>>(erow, ecol, ew, cnt, ell, E);

    const int LGRID = (n / RPW + 3) / 4;        // 1563
    const int PGRID = ((n >> 1) + 3) / 4;       // 6250 (row pairs)

    linear1_kernel<<<LGRID, 256, 0, stream>>>(node_feat, wp1, b1, s1, bufH1, n);
    gather_norm_kernel<<<PGRID, 256, 0, stream>>>(bufH1, cnt, ell, bufH2, n);
    linear2_kernel<<<LGRID, 256, 0, stream>>>(bufH2, wp2, b2, s2, bufH1, n);
    gather_logits_kernel<<<PGRID, 256, 0, stream>>>(bufH1, cnt, ell, cls, cb, outp, n);
}

// Round 23
// 230.230 us; speedup vs baseline: 1.2003x; 1.2003x over previous
//
#include <hip/hip_runtime.h>
#include <hip/hip_fp16.h>
#include <math.h>

#define NN 50000
#define DD 128
#define NCLS 40
#define EPSV 1e-8f
#define ELLCAP 64

typedef unsigned int uint4n __attribute__((ext_vector_type(4)));

__device__ __forceinline__ float waveReduceSum(float v) {
    for (int off = 32; off > 0; off >>= 1) v += __shfl_xor(v, off, 64);
    return v;
}

__device__ __forceinline__ float bcastlane0(float v) {
    return __int_as_float(__builtin_amdgcn_readfirstlane(__float_as_int(v)));
}

__device__ __forceinline__ float h_lo(unsigned int w) {
    return __half2float(__ushort_as_half((unsigned short)(w & 0xffffu)));
}
__device__ __forceinline__ float h_hi(unsigned int w) {
    return __half2float(__ushort_as_half((unsigned short)(w >> 16)));
}
__device__ __forceinline__ unsigned int h_pack(float a, float b) {
    return (unsigned int)__half_as_ushort(__float2half(a)) |
           ((unsigned int)__half_as_ushort(__float2half(b)) << 16);
}
__device__ __forceinline__ float fexp(float x) {
    return __builtin_amdgcn_exp2f(x * 1.44269504089f);
}
__device__ __forceinline__ float frcp(float x) { return __builtin_amdgcn_rcpf(x); }
__device__ __forceinline__ float frsq(float x) { return __builtin_amdgcn_rsqf(x); }

// ---------------- ELL build ----------------

__global__ void fill_ell_kernel(const int* __restrict__ erow, const int* __restrict__ ecol,
                                const float* __restrict__ ew, int* __restrict__ cnt,
                                unsigned int* __restrict__ ell, int E) {
    for (int e = blockIdx.x * blockDim.x + threadIdx.x; e < E; e += gridDim.x * blockDim.x) {
        int r = erow[e];
        int p = atomicAdd(&cnt[r], 1);
        if (p < ELLCAP) {
            unsigned int packed = (unsigned int)ecol[e] |
                ((unsigned int)__half_as_ushort(__float2half(ew[e])) << 16);
            ell[(long)r * ELLCAP + p] = packed;
        }
    }
}

__global__ void packwt_kernel(const float* __restrict__ W1, unsigned int* __restrict__ p1,
                              const float* __restrict__ W2, unsigned int* __restrict__ p2) {
    int b = blockIdx.x;
    const float* W = (b < 32) ? W1 : W2;
    unsigned int* P = (b < 32) ? p1 : p2;
    int a = (b & 31) * 256 + threadIdx.x;
    int pr = a >> 7;
    int rem = a & 127;
    int l = rem >> 1, kl = rem & 1;
    int k = 2 * pr + kl;
    P[a] = h_pack(W[(2 * l) * 128 + k], W[(2 * l + 1) * 128 + k]);
}

// ---------------- linear1: expmap + GEMM(fp16 W in LDS) + lorentz, fp16 out ----------------
// 512 threads: 8 waves share one 32KB wS + 8x4KB x slabs = 64KB -> 2 blocks/CU
// = 16 waves/CU = 4 waves/SIMD.
#define RPW 8
__global__ __launch_bounds__(512, 4) void linear1_kernel(
    const float* __restrict__ X, const unsigned int* __restrict__ Wp,
    const float* __restrict__ bias, const float* __restrict__ logs,
    unsigned int* __restrict__ outh, int n)
{
    __shared__ unsigned int wS[8192];        // 32KB fp16 W
    __shared__ float xrow[8][RPW * 128];     // 32KB
    int tid = threadIdx.x;
    int wid = tid >> 6, lane = tid & 63;
    #pragma unroll
    for (int i = 0; i < 4; ++i) {
        int idx = tid * 4 + i * 2048;
        *(uint4n*)(wS + idx) = *(const uint4n*)(Wp + idx);
    }
    __syncthreads();
    float2 bv = *(const float2*)(bias + 2 * lane);
    float sval = fminf(fexp(logs[0]), 10.f);
    float* xbase = xrow[wid];
    int nslabs = n / RPW;    // 6250
    for (int slab = blockIdx.x * 8 + wid; slab < nslabs; slab += gridDim.x * 8) {
        int row0 = slab * RPW;
        #pragma unroll
        for (int r = 0; r < RPW; ++r) {
            int row = row0 + r;
            const float* src = X + (long)row * 127;
            float u0 = src[2 * lane];
            float u1 = (2 * lane + 1 < 127) ? src[2 * lane + 1] : 0.f;
            float ss = waveReduceSum(u0 * u0 + u1 * u1);
            float nrm = fmaxf(sqrtf(ss), EPSV);
            float ex = fexp(nrm), exn = fexp(-nrm);
            float ch = 0.5f * (ex + exn);
            float coef = 0.5f * (ex - exn) * frcp(nrm);
            if (lane == 0) xbase[r * 128] = ch;
            xbase[r * 128 + 1 + 2 * lane] = coef * u0;
            if (2 * lane + 1 < 127) xbase[r * 128 + 2 + 2 * lane] = coef * u1;
        }
        float2 acc[RPW];
        #pragma unroll
        for (int r = 0; r < RPW; ++r) acc[r] = make_float2(0.f, 0.f);
        #pragma unroll 4
        for (int k0 = 0; k0 < 128; k0 += 4) {
            uint2 wa = *(const uint2*)(wS + (k0 >> 1) * 128 + 2 * lane);
            uint2 wb = *(const uint2*)(wS + (k0 >> 1) * 128 + 128 + 2 * lane);
            float2 w0 = make_float2(h_lo(wa.x), h_hi(wa.x));
            float2 w1 = make_float2(h_lo(wa.y), h_hi(wa.y));
            float2 w2 = make_float2(h_lo(wb.x), h_hi(wb.x));
            float2 w3 = make_float2(h_lo(wb.y), h_hi(wb.y));
            #pragma unroll
            for (int r = 0; r < RPW; ++r) {
                float4 xq = *(const float4*)(xbase + r * 128 + k0);
                acc[r].x = fmaf(xq.x, w0.x, acc[r].x);
                acc[r].y = fmaf(xq.x, w0.y, acc[r].y);
                acc[r].x = fmaf(xq.y, w1.x, acc[r].x);
                acc[r].y = fmaf(xq.y, w1.y, acc[r].y);
                acc[r].x = fmaf(xq.z, w2.x, acc[r].x);
                acc[r].y = fmaf(xq.z, w2.y, acc[r].y);
                acc[r].x = fmaf(xq.w, w3.x, acc[r].x);
                acc[r].y = fmaf(xq.w, w3.y, acc[r].y);
            }
        }
        #pragma unroll
        for (int r = 0; r < RPW; ++r) {
            float ax = acc[r].x + bv.x;
            float ay = acc[r].y + bv.y;
            float t0 = __shfl(ax, 0, 64);
            float ssq = waveReduceSum(ax * ax + ay * ay);
            float timev = sval * frcp(1.f + fexp(-t0)) + 1.5f;
            float sq = fmaxf(ssq - t0 * t0, EPSV);
            float fac = sqrtf(fmaxf((timev * timev - 1.f) * frcp(sq), EPSV));
            float o0 = (lane == 0) ? timev : ax * fac;
            __builtin_nontemporal_store(h_pack(o0, ay * fac),
                                        &outh[(long)(row0 + r) * 64 + lane]);
        }
    }
}

// ---------------- linear2: GEMM(fp16 W in LDS) on fp16 rows + lorentz, fp16 out ----------------
__global__ __launch_bounds__(512, 4) void linear2_kernel(
    const unsigned int* __restrict__ Xh, const unsigned int* __restrict__ Wp,
    const float* __restrict__ bias, const float* __restrict__ logs,
    unsigned int* __restrict__ outh, int n)
{
    __shared__ unsigned int wS[8192];
    __shared__ float xrow[8][RPW * 128];
    int tid = threadIdx.x;
    int wid = tid >> 6, lane = tid & 63;
    #pragma unroll
    for (int i = 0; i < 4; ++i) {
        int idx = tid * 4 + i * 2048;
        *(uint4n*)(wS + idx) = *(const uint4n*)(Wp + idx);
    }
    __syncthreads();
    float2 bv = *(const float2*)(bias + 2 * lane);
    float sval = fminf(fexp(logs[0]), 10.f);
    float* xbase = xrow[wid];
    int nslabs = n / RPW;
    for (int slab = blockIdx.x * 8 + wid; slab < nslabs; slab += gridDim.x * 8) {
        int row0 = slab * RPW;
        #pragma unroll
        for (int r = 0; r < RPW; ++r) {
            unsigned int u = __builtin_nontemporal_load(&Xh[(long)(row0 + r) * 64 + lane]);
            *(float2*)(xbase + r * 128 + 2 * lane) = make_float2(h_lo(u), h_hi(u));
        }
        float2 acc[RPW];
        #pragma unroll
        for (int r = 0; r < RPW; ++r) acc[r] = make_float2(0.f, 0.f);
        #pragma unroll 4
        for (int k0 = 0; k0 < 128; k0 += 4) {
            uint2 wa = *(const uint2*)(wS + (k0 >> 1) * 128 + 2 * lane);
            uint2 wb = *(const uint2*)(wS + (k0 >> 1) * 128 + 128 + 2 * lane);
            float2 w0 = make_float2(h_lo(wa.x), h_hi(wa.x));
            float2 w1 = make_float2(h_lo(wa.y), h_hi(wa.y));
            float2 w2 = make_float2(h_lo(wb.x), h_hi(wb.x));
            float2 w3 = make_float2(h_lo(wb.y), h_hi(wb.y));
            #pragma unroll
            for (int r = 0; r < RPW; ++r) {
                float4 xq = *(const float4*)(xbase + r * 128 + k0);
                acc[r].x = fmaf(xq.x, w0.x, acc[r].x);
                acc[r].y = fmaf(xq.x, w0.y, acc[r].y);
                acc[r].x = fmaf(xq.y, w1.x, acc[r].x);
                acc[r].y = fmaf(xq.y, w1.y, acc[r].y);
                acc[r].x = fmaf(xq.z, w2.x, acc[r].x);
                acc[r].y = fmaf(xq.z, w2.y, acc[r].y);
                acc[r].x = fmaf(xq.w, w3.x, acc[r].x);
                acc[r].y = fmaf(xq.w, w3.y, acc[r].y);
            }
        }
        #pragma unroll
        for (int r = 0; r < RPW; ++r) {
            float ax = acc[r].x + bv.x;
            float ay = acc[r].y + bv.y;
            float t0 = __shfl(ax, 0, 64);
            float ssq = waveReduceSum(ax * ax + ay * ay);
            float timev = sval * frcp(1.f + fexp(-t0)) + 1.5f;
            float sq = fmaxf(ssq - t0 * t0, EPSV);
            float fac = sqrtf(fmaxf((timev * timev - 1.f) * frcp(sq), EPSV));
            float o0 = (lane == 0) ? timev : ax * fac;
            __builtin_nontemporal_store(h_pack(o0, ay * fac),
                                        &outh[(long)(row0 + r) * 64 + lane]);
        }
    }
}

// ---------------- gather: 2 rows/wave, 4 groups, single-edge interleave (round-20) ----
// edge = packed uint: col (low 16) | fp16 weight (high 16)

#define GATHER_BODY(accs, eptr, idx)                                       \
    {                                                                      \
        unsigned int cw = eptr[idx];                                       \
        float w = h_hi(cw);                                                \
        uint4 xw = *(const uint4*)(Xh + (long)(cw & 0xffffu) * 64 + l16 * 4); \
        accs[0] = fmaf(w, h_lo(xw.x), accs[0]);                            \
        accs[1] = fmaf(w, h_hi(xw.x), accs[1]);                            \
        accs[2] = fmaf(w, h_lo(xw.y), accs[2]);                            \
        accs[3] = fmaf(w, h_hi(xw.y), accs[3]);                            \
        accs[4] = fmaf(w, h_lo(xw.z), accs[4]);                            \
        accs[5] = fmaf(w, h_hi(xw.z), accs[5]);                            \
        accs[6] = fmaf(w, h_lo(xw.w), accs[6]);                            \
        accs[7] = fmaf(w, h_hi(xw.w), accs[7]);                            \
    }

#define REDUCE8(accs)                                                      \
    _Pragma("unroll")                                                      \
    for (int q = 0; q < 8; ++q) {                                          \
        accs[q] += __shfl_xor(accs[q], 16, 64);                            \
        accs[q] += __shfl_xor(accs[q], 32, 64);                            \
    }

#define GATHER_PAIR()                                                      \
    int rowA = 2 * pair, rowB = rowA + 1;                                  \
    int cA = min(cnt[rowA], ELLCAP), cB = min(cnt[rowB], ELLCAP);          \
    const unsigned int* eA = ell + (long)rowA * ELLCAP;                    \
    const unsigned int* eB = ell + (long)rowB * ELLCAP;                    \
    float aA[8] = {0,0,0,0,0,0,0,0};                                       \
    float aB[8] = {0,0,0,0,0,0,0,0};                                       \
    {                                                                      \
        int ia = g, ib = g;                                                \
        while (ia < cA && ib < cB) {                                       \
            GATHER_BODY(aA, eA, ia)                                        \
            GATHER_BODY(aB, eB, ib)                                        \
            ia += 4; ib += 4;                                              \
        }                                                                  \
        while (ia < cA) { GATHER_BODY(aA, eA, ia) ia += 4; }               \
        while (ib < cB) { GATHER_BODY(aB, eB, ib) ib += 4; }               \
    }                                                                      \
    REDUCE8(aA)                                                            \
    REDUCE8(aB)

#define SS16(ss)                                                           \
    ss += __shfl_xor(ss, 1, 64); ss += __shfl_xor(ss, 2, 64);              \
    ss += __shfl_xor(ss, 4, 64); ss += __shfl_xor(ss, 8, 64);

// ---------------- agg1 + lorentz-normalize + relu -> fp16 ----------------
__global__ __launch_bounds__(256, 8) void gather_norm_kernel(
    const unsigned int* __restrict__ Xh, const int* __restrict__ cnt,
    const unsigned int* __restrict__ ell, unsigned int* __restrict__ outh, int n)
{
    int wid = threadIdx.x >> 6, lane = threadIdx.x & 63;
    int g = lane >> 4, l16 = lane & 15;
    int npairs = n >> 1;
    for (int pair = blockIdx.x * 4 + wid; pair < npairs; pair += gridDim.x * 4) {
        GATHER_PAIR()
        float ssA = aA[0]*aA[0]+aA[1]*aA[1]+aA[2]*aA[2]+aA[3]*aA[3]
                  + aA[4]*aA[4]+aA[5]*aA[5]+aA[6]*aA[6]+aA[7]*aA[7];
        float ssB = aB[0]*aB[0]+aB[1]*aB[1]+aB[2]*aB[2]+aB[3]*aB[3]
                  + aB[4]*aB[4]+aB[5]*aB[5]+aB[6]*aB[6]+aB[7]*aB[7];
        SS16(ssA)
        SS16(ssB)
        float t0A = bcastlane0(aA[0]);
        float t0B = bcastlane0(aB[0]);
        float invA = frsq(fmaxf(fabsf(2.f * t0A * t0A - ssA), EPSV));
        float invB = frsq(fmaxf(fabsf(2.f * t0B * t0B - ssB), EPSV));
        if (g == 0) {
            uint4n o;
            o.x = h_pack(fmaxf(aA[0]*invA,0.f), fmaxf(aA[1]*invA,0.f));
            o.y = h_pack(fmaxf(aA[2]*invA,0.f), fmaxf(aA[3]*invA,0.f));
            o.z = h_pack(fmaxf(aA[4]*invA,0.f), fmaxf(aA[5]*invA,0.f));
            o.w = h_pack(fmaxf(aA[6]*invA,0.f), fmaxf(aA[7]*invA,0.f));
            __builtin_nontemporal_store(o, (uint4n*)(outh + (long)rowA * 64 + l16 * 4));
        } else if (g == 1) {
            uint4n o;
            o.x = h_pack(fmaxf(aB[0]*invB,0.f), fmaxf(aB[1]*invB,0.f));
            o.y = h_pack(fmaxf(aB[2]*invB,0.f), fmaxf(aB[3]*invB,0.f));
            o.z = h_pack(fmaxf(aB[4]*invB,0.f), fmaxf(aB[5]*invB,0.f));
            o.w = h_pack(fmaxf(aB[6]*invB,0.f), fmaxf(aB[7]*invB,0.f));
            __builtin_nontemporal_store(o, (uint4n*)(outh + (long)rowB * 64 + l16 * 4));
        }
    }
}

// ---------------- agg2 + lorentz-normalize + sign-flip + logits ----------------
__global__ __launch_bounds__(256, 8) void gather_logits_kernel(
    const unsigned int* __restrict__ Xh, const int* __restrict__ cnt,
    const unsigned int* __restrict__ ell,
    const float* __restrict__ cls, const float* __restrict__ cbias,
    float* __restrict__ outp, int n)
{
    __shared__ unsigned int clsP[NCLS * 66];
    __shared__ float cbS[NCLS];
    __shared__ float xsrow[4][2][128];
    int tid = threadIdx.x;
    for (int idx = tid; idx < NCLS * 64; idx += 256) {
        int c = idx >> 6, kk = idx & 63;
        clsP[c * 66 + kk] = h_pack(cls[c * 128 + 2 * kk], cls[c * 128 + 2 * kk + 1]);
    }
    if (tid < NCLS) cbS[tid] = cbias[tid];
    __syncthreads();
    int wid = tid >> 6, lane = tid & 63;
    int g = lane >> 4, l16 = lane & 15;
    float* xsA = xsrow[wid][0];
    float* xsB = xsrow[wid][1];
    int npairs = n >> 1;
    for (int pair = blockIdx.x * 4 + wid; pair < npairs; pair += gridDim.x * 4) {
        GATHER_PAIR()
        float ssA = aA[0]*aA[0]+aA[1]*aA[1]+aA[2]*aA[2]+aA[3]*aA[3]
                  + aA[4]*aA[4]+aA[5]*aA[5]+aA[6]*aA[6]+aA[7]*aA[7];
        float ssB = aB[0]*aB[0]+aB[1]*aB[1]+aB[2]*aB[2]+aB[3]*aB[3]
                  + aB[4]*aB[4]+aB[5]*aB[5]+aB[6]*aB[6]+aB[7]*aB[7];
        SS16(ssA)
        SS16(ssB)
        float t0A = bcastlane0(aA[0]);
        float t0B = bcastlane0(aB[0]);
        float invA = frsq(fmaxf(fabsf(2.f * t0A * t0A - ssA), EPSV));
        float invB = frsq(fmaxf(fabsf(2.f * t0B * t0B - ssB), EPSV));
        if (g == 0) {
            float v0 = aA[0] * invA;
            if (l16 == 0) v0 = -v0;
            float* xp = xsA + l16 * 8;
            *(float4*)xp       = make_float4(v0, aA[1]*invA, aA[2]*invA, aA[3]*invA);
            *(float4*)(xp + 4) = make_float4(aA[4]*invA, aA[5]*invA, aA[6]*invA, aA[7]*invA);
        } else if (g == 1) {
            float v0 = aB[0] * invB;
            if (l16 == 0) v0 = -v0;
            float* xp = xsB + l16 * 8;
            *(float4*)xp       = make_float4(v0, aB[1]*invB, aB[2]*invB, aB[3]*invB);
            *(float4*)(xp + 4) = make_float4(aB[4]*invB, aB[5]*invB, aB[6]*invB, aB[7]*invB);
        }
        if (lane < NCLS) {
            float dA = 0.f, dB = 0.f;
            const unsigned int* cp = clsP + lane * 66;
            #pragma unroll 8
            for (int kk = 0; kk < 64; ++kk) {
                unsigned int u = cp[kk];
                float c0 = h_lo(u), c1 = h_hi(u);
                float2 xa = *(const float2*)(xsA + 2 * kk);
                float2 xb = *(const float2*)(xsB + 2 * kk);
                dA = fmaf(c0, xa.x, dA); dA = fmaf(c1, xa.y, dA);
                dB = fmaf(c0, xb.x, dB); dB = fmaf(c1, xb.y, dB);
            }
            outp[(long)rowA * NCLS + lane] = 2.f + 2.f * dA + cbS[lane];
            outp[(long)rowB * NCLS + lane] = 2.f + 2.f * dB + cbS[lane];
        }
    }
}

// ---------------- launch ----------------

extern "C" void kernel_launch(void* const* d_in, const int* in_sizes, int n_in,
                              void* d_out, int out_size, void* d_ws, size_t ws_size,
                              hipStream_t stream) {
    const float* node_feat = (const float*)d_in[0];
    const float* W1   = (const float*)d_in[1];
    const float* b1   = (const float*)d_in[2];
    const float* s1   = (const float*)d_in[3];
    const float* W2   = (const float*)d_in[4];
    const float* b2   = (const float*)d_in[5];
    const float* s2   = (const float*)d_in[6];
    const float* cls  = (const float*)d_in[7];
    const float* cb   = (const float*)d_in[8];
    const float* ew   = (const float*)d_in[9];
    const int*   erow = (const int*)d_in[10];
    const int*   ecol = (const int*)d_in[11];
    float* outp = (float*)d_out;

    const int n = NN;
    const int E = in_sizes[9];

    unsigned int* bufH1 = (unsigned int*)d_ws;
    unsigned int* bufH2 = bufH1 + (size_t)NN * 64;
    int*   cnt    = (int*)(bufH2 + (size_t)NN * 64);
    unsigned int* ell = (unsigned int*)(cnt + NN);
    unsigned int* wp1 = ell + (size_t)NN * ELLCAP;
    unsigned int* wp2 = wp1 + 128 * 64;

    (void)hipMemsetAsync(cnt, 0, (size_t)NN * sizeof(int), stream);
    packwt_kernel<<<64, 256, 0, stream>>>(W1, wp1, W2, wp2);
    fill_ell_kernel<<<2048, 256, 0, stream>>>(erow, ecol, ew, cnt, ell, E);

    const int LGRID = (n / RPW + 7) / 8;        // 782 (512-thread blocks)
    const int PGRID = ((n >> 1) + 3) / 4;       // 6250 (row pairs)

    linear1_kernel<<<LGRID, 512, 0, stream>>>(node_feat, wp1, b1, s1, bufH1, n);
    gather_norm_kernel<<<PGRID, 256, 0, stream>>>(bufH1, cnt, ell, bufH2, n);
    linear2_kernel<<<LGRID, 512, 0, stream>>>(bufH2, wp2, b2, s2, bufH1, n);
    gather_logits_kernel<<<PGRID, 256, 0, stream>>>(bufH1, cnt, ell, cls, cb, outp, n);
}

// Round 25
// 217.343 us; speedup vs baseline: 1.2714x; 1.0593x over previous
//
#include <hip/hip_runtime.h>
#include <hip/hip_fp16.h>
#include <math.h>

#define NN 50000
#define DD 128
#define NCLS 40
#define EPSV 1e-8f
#define ELLCAP 64

typedef unsigned int uint4n __attribute__((ext_vector_type(4)));
typedef _Float16 h2 __attribute__((ext_vector_type(2)));

__device__ __forceinline__ float h_lo(unsigned int w) {
    return __half2float(__ushort_as_half((unsigned short)(w & 0xffffu)));
}
__device__ __forceinline__ float h_hi(unsigned int w) {
    return __half2float(__ushort_as_half((unsigned short)(w >> 16)));
}

__device__ __forceinline__ h2 as_h2(unsigned int u) {
    union { unsigned int i; h2 h; } c; c.i = u; return c.h;
}

#if __has_builtin(__builtin_amdgcn_fdot2)
#define FDOT2(xu, wu, acc) acc = __builtin_amdgcn_fdot2(as_h2(xu), as_h2(wu), acc, false);
#else
#define FDOT2(xu, wu, acc)                                                  \
    {                                                                       \
        acc = fmaf(h_lo(xu), h_lo(wu), acc);                                \
        acc = fmaf(h_hi(xu), h_hi(wu), acc);                                \
    }
#endif

__device__ __forceinline__ float waveReduceSum(float v) {
    for (int off = 32; off > 0; off >>= 1) v += __shfl_xor(v, off, 64);
    return v;
}

__device__ __forceinline__ float bcastlane0(float v) {
    return __int_as_float(__builtin_amdgcn_readfirstlane(__float_as_int(v)));
}

__device__ __forceinline__ unsigned int h_pack(float a, float b) {
    return (unsigned int)__half_as_ushort(__float2half(a)) |
           ((unsigned int)__half_as_ushort(__float2half(b)) << 16);
}
__device__ __forceinline__ float fexp(float x) {
    return __builtin_amdgcn_exp2f(x * 1.44269504089f);
}
__device__ __forceinline__ float frcp(float x) { return __builtin_amdgcn_rcpf(x); }
__device__ __forceinline__ float frsq(float x) { return __builtin_amdgcn_rsqf(x); }

// ---------------- ELL build ----------------

__global__ void fill_ell_kernel(const int* __restrict__ erow, const int* __restrict__ ecol,
                                const float* __restrict__ ew, int* __restrict__ cnt,
                                unsigned int* __restrict__ ell, int E) {
    for (int e = blockIdx.x * blockDim.x + threadIdx.x; e < E; e += gridDim.x * blockDim.x) {
        int r = erow[e];
        int p = atomicAdd(&cnt[r], 1);
        if (p < ELLCAP) {
            unsigned int packed = (unsigned int)ecol[e] |
                ((unsigned int)__half_as_ushort(__float2half(ew[e])) << 16);
            ell[(long)r * ELLCAP + p] = packed;
        }
    }
}

// pack both W's as along-k fp16 pairs: P[kk*128 + col] = (W[col][2kk], W[col][2kk+1])
__global__ void packwt_kernel(const float* __restrict__ W1, unsigned int* __restrict__ p1,
                              const float* __restrict__ W2, unsigned int* __restrict__ p2) {
    int b = blockIdx.x;                       // 0..31 -> W1, 32..63 -> W2
    const float* W = (b < 32) ? W1 : W2;
    unsigned int* P = (b < 32) ? p1 : p2;
    int a = (b & 31) * 256 + threadIdx.x;     // 0..8191
    int kk = a >> 7, col = a & 127;
    P[a] = h_pack(W[col * 128 + 2 * kk], W[col * 128 + 2 * kk + 1]);
}

// ---------------- linear1: expmap + dot2-GEMM + lorentz, fp16 out ----------------
// fp16-overflow fix: stage x/ch (all components in [-1,1] since |space|<=cosh),
// ch is wave-uniform per row -> rescale fp32 acc by ch after the GEMM.
#define RPW 8
__global__ __launch_bounds__(512, 4) void linear1_kernel(
    const float* __restrict__ X, const unsigned int* __restrict__ Wp,
    const float* __restrict__ bias, const float* __restrict__ logs,
    unsigned int* __restrict__ outh, int n)
{
    __shared__ unsigned int wS[8192];        // 32KB: wS[kk*128+col]
    __shared__ unsigned int xS[8][RPW * 64]; // 16KB packed fp16 x/ch rows
    int tid = threadIdx.x;
    int wid = tid >> 6, lane = tid & 63;
    #pragma unroll
    for (int i = 0; i < 4; ++i) {
        int idx = tid * 4 + i * 2048;
        *(uint4n*)(wS + idx) = *(const uint4n*)(Wp + idx);
    }
    __syncthreads();
    float2 bv = *(const float2*)(bias + 2 * lane);
    float sval = fminf(fexp(logs[0]), 10.f);
    unsigned int* xbase = xS[wid];
    int nslabs = n / RPW;    // 6250
    for (int slab = blockIdx.x * 8 + wid; slab < nslabs; slab += gridDim.x * 8) {
        int row0 = slab * RPW;
        float chv[RPW];                      // wave-uniform per-row scale
        #pragma unroll
        for (int r = 0; r < RPW; ++r) {
            int row = row0 + r;
            const float* src = X + (long)row * 127;
            float u0 = src[2 * lane];
            float u1 = (2 * lane + 1 < 127) ? src[2 * lane + 1] : 0.f;
            float ss = waveReduceSum(u0 * u0 + u1 * u1);
            float nrm = fmaxf(sqrtf(ss), EPSV);
            float ex = fexp(nrm), exn = fexp(-nrm);
            float ch = 0.5f * (ex + exn);
            float coef = 0.5f * (ex - exn) * frcp(nrm);
            chv[r] = ch;
            float inv_ch = frcp(ch);
            // x[2l] = (l==0)? ch : coef*u[2l-1] (prev lane's u1); x[2l+1] = coef*u0
            float u1p = __shfl(u1, (lane + 63) & 63, 64);
            float xa = (lane == 0) ? 1.f : coef * u1p * inv_ch;   // scaled by 1/ch
            xbase[r * 64 + lane] = h_pack(xa, coef * u0 * inv_ch);
        }
        float2 acc[RPW];
        #pragma unroll
        for (int r = 0; r < RPW; ++r) acc[r] = make_float2(0.f, 0.f);
        #pragma unroll 4
        for (int kk0 = 0; kk0 < 64; kk0 += 4) {
            uint2 wp0 = *(const uint2*)(wS + (kk0 + 0) * 128 + 2 * lane);
            uint2 wp1 = *(const uint2*)(wS + (kk0 + 1) * 128 + 2 * lane);
            uint2 wp2 = *(const uint2*)(wS + (kk0 + 2) * 128 + 2 * lane);
            uint2 wp3 = *(const uint2*)(wS + (kk0 + 3) * 128 + 2 * lane);
            #pragma unroll
            for (int r = 0; r < RPW; ++r) {
                uint4 xq = *(const uint4*)(xbase + r * 64 + kk0);
                FDOT2(xq.x, wp0.x, acc[r].x) FDOT2(xq.x, wp0.y, acc[r].y)
                FDOT2(xq.y, wp1.x, acc[r].x) FDOT2(xq.y, wp1.y, acc[r].y)
                FDOT2(xq.z, wp2.x, acc[r].x) FDOT2(xq.z, wp2.y, acc[r].y)
                FDOT2(xq.w, wp3.x, acc[r].x) FDOT2(xq.w, wp3.y, acc[r].y)
            }
        }
        #pragma unroll
        for (int r = 0; r < RPW; ++r) {
            float ax = acc[r].x * chv[r] + bv.x;     // undo the 1/ch scale
            float ay = acc[r].y * chv[r] + bv.y;
            float t0 = __shfl(ax, 0, 64);
            float ssq = waveReduceSum(ax * ax + ay * ay);
            float timev = sval * frcp(1.f + fexp(-t0)) + 1.5f;
            float sq = fmaxf(ssq - t0 * t0, EPSV);
            float fac = sqrtf(fmaxf((timev * timev - 1.f) * frcp(sq), EPSV));
            float o0 = (lane == 0) ? timev : ax * fac;
            __builtin_nontemporal_store(h_pack(o0, ay * fac),
                                        &outh[(long)(row0 + r) * 64 + lane]);
        }
    }
}

// ---------------- linear2: dot2-GEMM on packed fp16 rows (no cvt staging) ----------------
__global__ __launch_bounds__(512, 4) void linear2_kernel(
    const unsigned int* __restrict__ Xh, const unsigned int* __restrict__ Wp,
    const float* __restrict__ bias, const float* __restrict__ logs,
    unsigned int* __restrict__ outh, int n)
{
    __shared__ unsigned int wS[8192];
    __shared__ unsigned int xS[8][RPW * 64];
    int tid = threadIdx.x;
    int wid = tid >> 6, lane = tid & 63;
    #pragma unroll
    for (int i = 0; i < 4; ++i) {
        int idx = tid * 4 + i * 2048;
        *(uint4n*)(wS + idx) = *(const uint4n*)(Wp + idx);
    }
    __syncthreads();
    float2 bv = *(const float2*)(bias + 2 * lane);
    float sval = fminf(fexp(logs[0]), 10.f);
    unsigned int* xbase = xS[wid];
    int nslabs = n / RPW;
    for (int slab = blockIdx.x * 8 + wid; slab < nslabs; slab += gridDim.x * 8) {
        int row0 = slab * RPW;
        #pragma unroll
        for (int r = 0; r < RPW; ++r)
            xbase[r * 64 + lane] =
                __builtin_nontemporal_load(&Xh[(long)(row0 + r) * 64 + lane]);
        float2 acc[RPW];
        #pragma unroll
        for (int r = 0; r < RPW; ++r) acc[r] = make_float2(0.f, 0.f);
        #pragma unroll 4
        for (int kk0 = 0; kk0 < 64; kk0 += 4) {
            uint2 wp0 = *(const uint2*)(wS + (kk0 + 0) * 128 + 2 * lane);
            uint2 wp1 = *(const uint2*)(wS + (kk0 + 1) * 128 + 2 * lane);
            uint2 wp2 = *(const uint2*)(wS + (kk0 + 2) * 128 + 2 * lane);
            uint2 wp3 = *(const uint2*)(wS + (kk0 + 3) * 128 + 2 * lane);
            #pragma unroll
            for (int r = 0; r < RPW; ++r) {
                uint4 xq = *(const uint4*)(xbase + r * 64 + kk0);
                FDOT2(xq.x, wp0.x, acc[r].x) FDOT2(xq.x, wp0.y, acc[r].y)
                FDOT2(xq.y, wp1.x, acc[r].x) FDOT2(xq.y, wp1.y, acc[r].y)
                FDOT2(xq.z, wp2.x, acc[r].x) FDOT2(xq.z, wp2.y, acc[r].y)
                FDOT2(xq.w, wp3.x, acc[r].x) FDOT2(xq.w, wp3.y, acc[r].y)
            }
        }
        #pragma unroll
        for (int r = 0; r < RPW; ++r) {
            float ax = acc[r].x + bv.x;
            float ay = acc[r].y + bv.y;
            float t0 = __shfl(ax, 0, 64);
            float ssq = waveReduceSum(ax * ax + ay * ay);
            float timev = sval * frcp(1.f + fexp(-t0)) + 1.5f;
            float sq = fmaxf(ssq - t0 * t0, EPSV);
            float fac = sqrtf(fmaxf((timev * timev - 1.f) * frcp(sq), EPSV));
            float o0 = (lane == 0) ? timev : ax * fac;
            __builtin_nontemporal_store(h_pack(o0, ay * fac),
                                        &outh[(long)(row0 + r) * 64 + lane]);
        }
    }
}

// ---------------- gather: 2 rows/wave, 4 groups, single-edge interleave ----------------
// edge = packed uint: col (low 16) | fp16 weight (high 16)

#define GATHER_BODY(accs, eptr, idx)                                       \
    {                                                                      \
        unsigned int cw = eptr[idx];                                       \
        float w = h_hi(cw);                                                \
        uint4 xw = *(const uint4*)(Xh + (long)(cw & 0xffffu) * 64 + l16 * 4); \
        accs[0] = fmaf(w, h_lo(xw.x), accs[0]);                            \
        accs[1] = fmaf(w, h_hi(xw.x), accs[1]);                            \
        accs[2] = fmaf(w, h_lo(xw.y), accs[2]);                            \
        accs[3] = fmaf(w, h_hi(xw.y), accs[3]);                            \
        accs[4] = fmaf(w, h_lo(xw.z), accs[4]);                            \
        accs[5] = fmaf(w, h_hi(xw.z), accs[5]);                            \
        accs[6] = fmaf(w, h_lo(xw.w), accs[6]);                            \
        accs[7] = fmaf(w, h_hi(xw.w), accs[7]);                            \
    }

#define REDUCE8(accs)                                                      \
    _Pragma("unroll")                                                      \
    for (int q = 0; q < 8; ++q) {                                          \
        accs[q] += __shfl_xor(accs[q], 16, 64);                            \
        accs[q] += __shfl_xor(accs[q], 32, 64);                            \
    }

#define GATHER_PAIR()                                                      \
    int rowA = 2 * pair, rowB = rowA + 1;                                  \
    int cA = min(cnt[rowA], ELLCAP), cB = min(cnt[rowB], ELLCAP);          \
    const unsigned int* eA = ell + (long)rowA * ELLCAP;                    \
    const unsigned int* eB = ell + (long)rowB * ELLCAP;                    \
    float aA[8] = {0,0,0,0,0,0,0,0};                                       \
    float aB[8] = {0,0,0,0,0,0,0,0};                                       \
    {                                                                      \
        int ia = g, ib = g;                                                \
        while (ia < cA && ib < cB) {                                       \
            GATHER_BODY(aA, eA, ia)                                        \
            GATHER_BODY(aB, eB, ib)                                        \
            ia += 4; ib += 4;                                              \
        }                                                                  \
        while (ia < cA) { GATHER_BODY(aA, eA, ia) ia += 4; }               \
        while (ib < cB) { GATHER_BODY(aB, eB, ib) ib += 4; }               \
    }                                                                      \
    REDUCE8(aA)                                                            \
    REDUCE8(aB)

#define SS16(ss)                                                           \
    ss += __shfl_xor(ss, 1, 64); ss += __shfl_xor(ss, 2, 64);              \
    ss += __shfl_xor(ss, 4, 64); ss += __shfl_xor(ss, 8, 64);

// ---------------- agg1 + lorentz-normalize + relu -> fp16 ----------------
__global__ __launch_bounds__(256, 8) void gather_norm_kernel(
    const unsigned int* __restrict__ Xh, const int* __restrict__ cnt,
    const unsigned int* __restrict__ ell, unsigned int* __restrict__ outh, int n)
{
    int wid = threadIdx.x >> 6, lane = threadIdx.x & 63;
    int g = lane >> 4, l16 = lane & 15;
    int npairs = n >> 1;
    for (int pair = blockIdx.x * 4 + wid; pair < npairs; pair += gridDim.x * 4) {
        GATHER_PAIR()
        float ssA = aA[0]*aA[0]+aA[1]*aA[1]+aA[2]*aA[2]+aA[3]*aA[3]
                  + aA[4]*aA[4]+aA[5]*aA[5]+aA[6]*aA[6]+aA[7]*aA[7];
        float ssB = aB[0]*aB[0]+aB[1]*aB[1]+aB[2]*aB[2]+aB[3]*aB[3]
                  + aB[4]*aB[4]+aB[5]*aB[5]+aB[6]*aB[6]+aB[7]*aB[7];
        SS16(ssA)
        SS16(ssB)
        float t0A = bcastlane0(aA[0]);
        float t0B = bcastlane0(aB[0]);
        float invA = frsq(fmaxf(fabsf(2.f * t0A * t0A - ssA), EPSV));
        float invB = frsq(fmaxf(fabsf(2.f * t0B * t0B - ssB), EPSV));
        if (g == 0) {
            uint4n o;
            o.x = h_pack(fmaxf(aA[0]*invA,0.f), fmaxf(aA[1]*invA,0.f));
            o.y = h_pack(fmaxf(aA[2]*invA,0.f), fmaxf(aA[3]*invA,0.f));
            o.z = h_pack(fmaxf(aA[4]*invA,0.f), fmaxf(aA[5]*invA,0.f));
            o.w = h_pack(fmaxf(aA[6]*invA,0.f), fmaxf(aA[7]*invA,0.f));
            __builtin_nontemporal_store(o, (uint4n*)(outh + (long)rowA * 64 + l16 * 4));
        } else if (g == 1) {
            uint4n o;
            o.x = h_pack(fmaxf(aB[0]*invB,0.f), fmaxf(aB[1]*invB,0.f));
            o.y = h_pack(fmaxf(aB[2]*invB,0.f), fmaxf(aB[3]*invB,0.f));
            o.z = h_pack(fmaxf(aB[4]*invB,0.f), fmaxf(aB[5]*invB,0.f));
            o.w = h_pack(fmaxf(aB[6]*invB,0.f), fmaxf(aB[7]*invB,0.f));
            __builtin_nontemporal_store(o, (uint4n*)(outh + (long)rowB * 64 + l16 * 4));
        }
    }
}

// ---------------- agg2 + lorentz-normalize + sign-flip + logits ----------------
__global__ __launch_bounds__(256, 8) void gather_logits_kernel(
    const unsigned int* __restrict__ Xh, const int* __restrict__ cnt,
    const unsigned int* __restrict__ ell,
    const float* __restrict__ cls, const float* __restrict__ cbias,
    float* __restrict__ outp, int n)
{
    __shared__ unsigned int clsP[NCLS * 66];
    __shared__ float cbS[NCLS];
    __shared__ float xsrow[4][2][128];
    int tid = threadIdx.x;
    for (int idx = tid; idx < NCLS * 64; idx += 256) {
        int c = idx >> 6, kk = idx & 63;
        clsP[c * 66 + kk] = h_pack(cls[c * 128 + 2 * kk], cls[c * 128 + 2 * kk + 1]);
    }
    if (tid < NCLS) cbS[tid] = cbias[tid];
    __syncthreads();
    int wid = tid >> 6, lane = tid & 63;
    int g = lane >> 4, l16 = lane & 15;
    float* xsA = xsrow[wid][0];
    float* xsB = xsrow[wid][1];
    int npairs = n >> 1;
    for (int pair = blockIdx.x * 4 + wid; pair < npairs; pair += gridDim.x * 4) {
        GATHER_PAIR()
        float ssA = aA[0]*aA[0]+aA[1]*aA[1]+aA[2]*aA[2]+aA[3]*aA[3]
                  + aA[4]*aA[4]+aA[5]*aA[5]+aA[6]*aA[6]+aA[7]*aA[7];
        float ssB = aB[0]*aB[0]+aB[1]*aB[1]+aB[2]*aB[2]+aB[3]*aB[3]
                  + aB[4]*aB[4]+aB[5]*aB[5]+aB[6]*aB[6]+aB[7]*aB[7];
        SS16(ssA)
        SS16(ssB)
        float t0A = bcastlane0(aA[0]);
        float t0B = bcastlane0(aB[0]);
        float invA = frsq(fmaxf(fabsf(2.f * t0A * t0A - ssA), EPSV));
        float invB = frsq(fmaxf(fabsf(2.f * t0B * t0B - ssB), EPSV));
        if (g == 0) {
            float v0 = aA[0] * invA;
            if (l16 == 0) v0 = -v0;
            float* xp = xsA + l16 * 8;
            *(float4*)xp       = make_float4(v0, aA[1]*invA, aA[2]*invA, aA[3]*invA);
            *(float4*)(xp + 4) = make_float4(aA[4]*invA, aA[5]*invA, aA[6]*invA, aA[7]*invA);
        } else if (g == 1) {
            float v0 = aB[0] * invB;
            if (l16 == 0) v0 = -v0;
            float* xp = xsB + l16 * 8;
            *(float4*)xp       = make_float4(v0, aB[1]*invB, aB[2]*invB, aB[3]*invB);
            *(float4*)(xp + 4) = make_float4(aB[4]*invB, aB[5]*invB, aB[6]*invB, aB[7]*invB);
        }
        if (lane < NCLS) {
            float dA = 0.f, dB = 0.f;
            const unsigned int* cp = clsP + lane * 66;
            #pragma unroll 8
            for (int kk = 0; kk < 64; ++kk) {
                unsigned int u = cp[kk];
                float c0 = h_lo(u), c1 = h_hi(u);
                float2 xa = *(const float2*)(xsA + 2 * kk);
                float2 xb = *(const float2*)(xsB + 2 * kk);
                dA = fmaf(c0, xa.x, dA); dA = fmaf(c1, xa.y, dA);
                dB = fmaf(c0, xb.x, dB); dB = fmaf(c1, xb.y, dB);
            }
            outp[(long)rowA * NCLS + lane] = 2.f + 2.f * dA + cbS[lane];
            outp[(long)rowB * NCLS + lane] = 2.f + 2.f * dB + cbS[lane];
        }
    }
}

// ---------------- launch ----------------

extern "C" void kernel_launch(void* const* d_in, const int* in_sizes, int n_in,
                              void* d_out, int out_size, void* d_ws, size_t ws_size,
                              hipStream_t stream) {
    const float* node_feat = (const float*)d_in[0];
    const float* W1   = (const float*)d_in[1];
    const float* b1   = (const float*)d_in[2];
    const float* s1   = (const float*)d_in[3];
    const float* W2   = (const float*)d_in[4];
    const float* b2   = (const float*)d_in[5];
    const float* s2   = (const float*)d_in[6];
    const float* cls  = (const float*)d_in[7];
    const float* cb   = (const float*)d_in[8];
    const float* ew   = (const float*)d_in[9];
    const int*   erow = (const int*)d_in[10];
    const int*   ecol = (const int*)d_in[11];
    float* outp = (float*)d_out;

    const int n = NN;
    const int E = in_sizes[9];

    unsigned int* bufH1 = (unsigned int*)d_ws;
    unsigned int* bufH2 = bufH1 + (size_t)NN * 64;
    int*   cnt    = (int*)(bufH2 + (size_t)NN * 64);
    unsigned int* ell = (unsigned int*)(cnt + NN);
    unsigned int* wp1 = ell + (size_t)NN * ELLCAP;
    unsigned int* wp2 = wp1 + 128 * 64;

    (void)hipMemsetAsync(cnt, 0, (size_t)NN * sizeof(int), stream);
    packwt_kernel<<<64, 256, 0, stream>>>(W1, wp1, W2, wp2);
    fill_ell_kernel<<<2048, 256, 0, stream>>>(erow, ecol, ew, cnt, ell, E);

    const int LGRID = (n / RPW + 7) / 8;        // 782 (512-thread blocks)
    const int PGRID = ((n >> 1) + 3) / 4;       // 6250 (row pairs)

    linear1_kernel<<<LGRID, 512, 0, stream>>>(node_feat, wp1, b1, s1, bufH1, n);
    gather_norm_kernel<<<PGRID, 256, 0, stream>>>(bufH1, cnt, ell, bufH2, n);
    linear2_kernel<<<LGRID, 512, 0, stream>>>(bufH2, wp2, b2, s2, bufH1, n);
    gather_logits_kernel<<<PGRID, 256, 0, stream>>>(bufH1, cnt, ell, cls, cb, outp, n);
}